// Round 9
// baseline (501.336 us; speedup 1.0000x reference)
//
#include <hip/hip_runtime.h>
#include <hip/hip_bf16.h>
#include <cstdint>

typedef __attribute__((ext_vector_type(8))) short short8;
typedef __attribute__((ext_vector_type(4))) short short4v;
typedef __attribute__((ext_vector_type(4))) float floatx4;

constexpr int B_ = 2, L_ = 4096, D_ = 1024, H_ = 16, DH = 64, F_ = 4096;
constexpr int M_ = B_ * L_;        // 8192 rows
constexpr int NQKV = 3 * D_;       // 3072
constexpr int VT_GUARD = 512;

// ---------------- workspace layout (bytes) ----------------
constexpr size_t OFF_XB  = 0;                                       // bf16 [M][D]
constexpr size_t OFF_WCT = OFF_XB  + (size_t)M_ * D_ * 2;           // bf16 [3072][1024]
constexpr size_t OFF_W1T = OFF_WCT + (size_t)NQKV * D_ * 2;         // bf16 [4096][1024]
constexpr size_t OFF_W2T = OFF_W1T + (size_t)F_ * D_ * 2;           // bf16 [1024][4096]
constexpr size_t OFF_QKV = OFF_W2T + (size_t)D_ * F_ * 2;           // bf16 [M][3072]
constexpr size_t OFF_VT  = OFF_QKV + (size_t)M_ * NQKV * 2;
constexpr size_t OFF_ATT = OFF_VT  + ((size_t)B_*H_*DH*L_ + 2*VT_GUARD) * 2;
constexpr size_t OFF_HB  = OFF_ATT + (size_t)M_ * D_ * 2;
constexpr size_t OFF_MID = OFF_HB  + (size_t)M_ * D_ * 2;           // bf16 [M][F]

static __device__ __forceinline__ float b2f(unsigned short u) {
    union { unsigned int i; float f; } v; v.i = ((unsigned int)u) << 16; return v.f;
}

static __device__ __forceinline__ void gload16(const void* g, void* l) {
    __builtin_amdgcn_global_load_lds(
        (const __attribute__((address_space(1))) uint32_t*)g,
        (__attribute__((address_space(3))) uint32_t*)l, 16, 0, 0);
}

// ---------------- f32 -> bf16 convert (x) ----------------
__global__ __launch_bounds__(256) void k_cvt_x(const float* __restrict__ x,
                                               __hip_bfloat16* __restrict__ xb) {
    int i = (blockIdx.x * 256 + threadIdx.x) * 8;
    float4 a = *(const float4*)(x + i);
    float4 b = *(const float4*)(x + i + 4);
    alignas(16) __hip_bfloat16 t[8];
    t[0] = __float2bfloat16(a.x); t[1] = __float2bfloat16(a.y);
    t[2] = __float2bfloat16(a.z); t[3] = __float2bfloat16(a.w);
    t[4] = __float2bfloat16(b.x); t[5] = __float2bfloat16(b.y);
    t[6] = __float2bfloat16(b.z); t[7] = __float2bfloat16(b.w);
    *(uint4*)(xb + i) = *(const uint4*)t;
}

// ---------------- transpose+convert: in [R][C] f32 -> out [C][R] bf16 ----------------
__global__ __launch_bounds__(256) void k_tcvt(const float* __restrict__ in,
                                              __hip_bfloat16* __restrict__ out,
                                              int R, int C) {
    __shared__ float t[64][65];
    int tx = threadIdx.x & 63, ty4 = threadIdx.x >> 6;
    int c0 = blockIdx.x * 64, r0 = blockIdx.y * 64;
#pragma unroll
    for (int i = 0; i < 16; i++) {
        int r = ty4 + i * 4;
        t[r][tx] = in[(size_t)(r0 + r) * C + c0 + tx];
    }
    __syncthreads();
#pragma unroll
    for (int i = 0; i < 16; i++) {
        int r = ty4 + i * 4;
        out[(size_t)(c0 + r) * R + r0 + tx] = __float2bfloat16(t[tx][r]);
    }
}

// ---------------- V transpose ----------------
__global__ __launch_bounds__(256) void k_vtrans(const __hip_bfloat16* __restrict__ qkv,
                                                __hip_bfloat16* __restrict__ vtg) {
    __shared__ __hip_bfloat16 t[64][72];
    int tx = threadIdx.x & 63, ty4 = threadIdx.x >> 6;
    int bh = blockIdx.y, b = bh >> 4, h = bh & 15;
    int j0 = blockIdx.x * 64;
#pragma unroll
    for (int i = 0; i < 16; i++) {
        int j = ty4 + i * 4;
        t[j][tx] = qkv[(size_t)(b * L_ + j0 + j) * NQKV + 2 * D_ + h * DH + tx];
    }
    __syncthreads();
#pragma unroll
    for (int i = 0; i < 16; i++) {
        int d = ty4 + i * 4;
        vtg[(long)(bh * DH + d) * L_ + j0 + tx] = t[tx][d];
    }
}

// ---------------- 128x256 4-wave MF8/NF4 triple-buffered GEMM (QKV/FFN1) ----------------
// C[8192][NBN*256] = A[8192][1024] * BT[NBN*256][1024]^T.
// 256 thr = 4 waves; each wave computes 128x64 (MF=8 m-frags x NF=4 n-frags) -> 32
// MFMA per 12 ds_reads per K-tile (B-frags read once, reused across all 8 m-frags).
// BK=32, triple-buffered LDS, stage t+2 during t, counted vmcnt(6) (never 0).
// Compile-time x3-unrolled buffer rotation (no runtime LDS base selects).
template<int GM, int EPI, int NBN>
__global__ __launch_bounds__(256, 2)
void k_w8(const __hip_bfloat16* __restrict__ A, const __hip_bfloat16* __restrict__ BT,
          const float* __restrict__ b0p, const float* __restrict__ b1p,
          const float* __restrict__ b2p,
          __hip_bfloat16* __restrict__ obf, float* __restrict__ of32) {
    constexpr int KTOT = 1024;
    constexpr int KT = KTOT / 32;            // 32
    constexpr int PER = GM * NBN;

    __shared__ __hip_bfloat16 AS[3][128 * 32];
    __shared__ __hip_bfloat16 BS[3][256 * 32];

    const int tid = threadIdx.x, wave = tid >> 6, lane = tid & 63;
    const int lo = lane & 15, hi = lane >> 4;
    const int wn = wave;                     // 4 n-waves, all share A rows

    // bijective XCD swizzle + group-major
    const int nwg = gridDim.x, q = nwg >> 3;
    const int bid = blockIdx.x;
    const int swz = (bid & 7) * q + (bid >> 3);
    const int g = swz / PER, r = swz % PER;
    const int bm = g * GM + (r % GM);
    const int bn = r / GM;
    const size_t m0 = (size_t)bm * 128, n0 = (size_t)bn * 256;

    // staging: thread row r0 = tid>>2 (sweeps of 64 rows), pre-swizzled global chunk
    const int r0 = tid >> 2;
    const int gcc = (tid & 3) ^ (r0 & 3);
    const __hip_bfloat16* aG = A  + (m0 + r0) * (size_t)KTOT + gcc * 8;
    const __hip_bfloat16* bG = BT + (n0 + r0) * (size_t)KTOT + gcc * 8;

    // fragment read bases: elem = row*32 + (hi^(row&3))*8, row&3 == lo&3
    const int cR = (hi ^ (lo & 3)) * 8;
    const int aOff = lo * 32 + cR;                 // + f*512 for m-frag f
    const int bOff = (wn * 64 + lo) * 32 + cR;     // + gf*512 for n-frag gf

    floatx4 acc[8][4] = {};

#define STAGE(buf, kt)                                                        \
    do {                                                                      \
        _Pragma("unroll")                                                     \
        for (int s = 0; s < 2; ++s)                                           \
            gload16(aG + (size_t)(s * 64) * KTOT + (size_t)(kt) * 32,         \
                    &AS[buf][(s * 256 + wave * 64) * 8]);                     \
        _Pragma("unroll")                                                     \
        for (int s = 0; s < 4; ++s)                                           \
            gload16(bG + (size_t)(s * 64) * KTOT + (size_t)(kt) * 32,         \
                    &BS[buf][(s * 256 + wave * 64) * 8]);                     \
    } while (0)

#define BODY(t, CUR, NB)                                                      \
    do {                                                                      \
        const int tf = ((t) + 2 < KT) ? (t) + 2 : (t);                        \
        STAGE(NB, tf);                                                        \
        short8 bfr[4], afr[8];                                                \
        _Pragma("unroll")                                                     \
        for (int gf = 0; gf < 4; ++gf)                                        \
            bfr[gf] = *(const short8*)(&BS[CUR][0] + bOff + gf * 512);        \
        _Pragma("unroll")                                                     \
        for (int f = 0; f < 8; ++f)                                           \
            afr[f] = *(const short8*)(&AS[CUR][0] + aOff + f * 512);          \
        __builtin_amdgcn_s_setprio(1);                                        \
        _Pragma("unroll")                                                     \
        for (int mf = 0; mf < 8; ++mf)                                        \
            _Pragma("unroll")                                                 \
            for (int nf = 0; nf < 4; ++nf)                                    \
                acc[mf][nf] = __builtin_amdgcn_mfma_f32_16x16x32_bf16(        \
                    afr[mf], bfr[nf], acc[mf][nf], 0, 0, 0);                  \
        __builtin_amdgcn_s_setprio(0);                                        \
        asm volatile("s_waitcnt vmcnt(6)" ::: "memory");                      \
        __builtin_amdgcn_sched_barrier(0);                                    \
        __builtin_amdgcn_s_barrier();                                         \
    } while (0)

    // prologue: stage tiles 0 and 1; drain tile 0's 6 loads only
    STAGE(0, 0);
    STAGE(1, 1);
    asm volatile("s_waitcnt vmcnt(6)" ::: "memory");
    __builtin_amdgcn_sched_barrier(0);
    __builtin_amdgcn_s_barrier();

    // KT = 32 = 10*3 + 2: static 3-way rotation, no runtime buffer selects
#pragma unroll 1
    for (int t = 0; t + 3 <= KT; t += 3) {
        BODY(t,     0, 2);
        BODY(t + 1, 1, 0);
        BODY(t + 2, 2, 1);
    }
    BODY(KT - 2, 0, 2);
    BODY(KT - 1, 1, 0);
#undef STAGE
#undef BODY

    // ---- epilogue ----
#pragma unroll
    for (int mf = 0; mf < 8; ++mf) {
        const int row = (int)m0 + mf * 16 + hi * 4;
#pragma unroll
        for (int gf = 0; gf < 4; ++gf) {
            const int col = (int)n0 + wn * 64 + gf * 16 + lo;
#pragma unroll
            for (int rr = 0; rr < 4; ++rr) {
                float v = acc[mf][gf][rr];
                const size_t ro = (size_t)(row + rr);
                if (EPI == 0) {
                    float bia = (col < 1024) ? b0p[col]
                              : (col < 2048 ? b1p[col - 1024] : b2p[col - 2048]);
                    obf[ro * NQKV + col] = __float2bfloat16(v + bia);
                } else {
                    v += b0p[col];
                    v = 0.5f * v * (1.0f + erff(v * 0.70710678118654752440f));
                    obf[ro * F_ + col] = __float2bfloat16(v);
                }
            }
        }
    }
    (void)of32;
}

// ---------------- 128xBN BK=32 triple-buffered pipeline GEMM (FFN2 control) ----------------
template<int NT, int WN, int GM, int EPI, int KTOT, int NBN, int MINW>
__global__ __launch_bounds__(NT, MINW)
void k_p3(const __hip_bfloat16* __restrict__ A, const __hip_bfloat16* __restrict__ BT,
          const float* __restrict__ b0p,
          __hip_bfloat16* __restrict__ obf, float* __restrict__ of32,
          const __hip_bfloat16* __restrict__ hres) {
    constexpr int BN = WN * 64;
    constexpr int KT = KTOT / 32;
    constexpr int PER = GM * NBN;
    constexpr int A_LOADS = (128 * 4) / NT;
    constexpr int B_LOADS = (BN * 4) / NT;
    constexpr int LPT = A_LOADS + B_LOADS;
    constexpr int RSWEEP = NT / 4;

    __shared__ __hip_bfloat16 AS[3][128 * 32];
    __shared__ __hip_bfloat16 BS[3][BN * 32];

    const int tid = threadIdx.x, wave = tid >> 6, lane = tid & 63;
    const int lo = lane & 15, hi = lane >> 4;
    const int wm = wave / WN, wn = wave % WN;

    const int nwg = gridDim.x, q = nwg >> 3;
    const int bid = blockIdx.x;
    const int swz = (bid & 7) * q + (bid >> 3);
    const int g = swz / PER, r = swz % PER;
    const int bm = g * GM + (r % GM);
    const int bn = r / GM;
    const size_t m0 = (size_t)bm * 128, n0 = (size_t)bn * BN;

    const int r0 = tid >> 2;
    const int gcc = (tid & 3) ^ (r0 & 3);
    const __hip_bfloat16* aG = A  + (m0 + r0) * (size_t)KTOT + gcc * 8;
    const __hip_bfloat16* bG = BT + (n0 + r0) * (size_t)KTOT + gcc * 8;

    const int cR = (hi ^ (lo & 3)) * 8;
    const int aOff = (wm * 64 + lo) * 32 + cR;
    const int bOff = (wn * 64 + lo) * 32 + cR;

    floatx4 acc[4][4] = {};

#define STAGE(buf, kt)                                                        \
    do {                                                                      \
        _Pragma("unroll")                                                     \
        for (int s = 0; s < A_LOADS; ++s)                                     \
            gload16(aG + (size_t)(s * RSWEEP) * KTOT + (size_t)(kt) * 32,     \
                    &AS[buf][(s * NT + wave * 64) * 8]);                      \
        _Pragma("unroll")                                                     \
        for (int s = 0; s < B_LOADS; ++s)                                     \
            gload16(bG + (size_t)(s * RSWEEP) * KTOT + (size_t)(kt) * 32,     \
                    &BS[buf][(s * NT + wave * 64) * 8]);                      \
    } while (0)

#define WAITVM_LPT()                                                          \
    do {                                                                      \
        if constexpr (LPT == 3) asm volatile("s_waitcnt vmcnt(3)" ::: "memory"); \
        else                    asm volatile("s_waitcnt vmcnt(4)" ::: "memory"); \
    } while (0)

#define BODY(t, CUR, NB)                                                      \
    do {                                                                      \
        const int tf = ((t) + 2 < KT) ? (t) + 2 : (t);                        \
        STAGE(NB, tf);                                                        \
        short8 afr[4], bfr[4];                                                \
        _Pragma("unroll")                                                     \
        for (int f = 0; f < 4; ++f) {                                         \
            afr[f] = *(const short8*)(&AS[CUR][0] + aOff + f * 512);          \
            bfr[f] = *(const short8*)(&BS[CUR][0] + bOff + f * 512);          \
        }                                                                     \
        __builtin_amdgcn_s_setprio(1);                                        \
        _Pragma("unroll")                                                     \
        for (int mf = 0; mf < 4; ++mf)                                        \
            _Pragma("unroll")                                                 \
            for (int nf = 0; nf < 4; ++nf)                                    \
                acc[mf][nf] = __builtin_amdgcn_mfma_f32_16x16x32_bf16(        \
                    afr[mf], bfr[nf], acc[mf][nf], 0, 0, 0);                  \
        __builtin_amdgcn_s_setprio(0);                                        \
        WAITVM_LPT();                                                         \
        __builtin_amdgcn_sched_barrier(0);                                    \
        __builtin_amdgcn_s_barrier();                                         \
    } while (0)

    STAGE(0, 0);
    STAGE(1, 1);
    WAITVM_LPT();
    __builtin_amdgcn_sched_barrier(0);
    __builtin_amdgcn_s_barrier();

    // KT % 3 == 2 for KT in {32, 128}
#pragma unroll 1
    for (int t = 0; t + 3 <= KT; t += 3) {
        BODY(t,     0, 2);
        BODY(t + 1, 1, 0);
        BODY(t + 2, 2, 1);
    }
    BODY(KT - 2, 0, 2);
    BODY(KT - 1, 1, 0);
#undef STAGE
#undef WAITVM_LPT
#undef BODY

    // ---- epilogue (EPI==2: bias + residual -> f32 out) ----
#pragma unroll
    for (int mf = 0; mf < 4; ++mf) {
        const int row = (int)m0 + wm * 64 + mf * 16 + hi * 4;
#pragma unroll
        for (int nf = 0; nf < 4; ++nf) {
            const int col = (int)n0 + wn * 64 + nf * 16 + lo;
#pragma unroll
            for (int rr = 0; rr < 4; ++rr) {
                float v = acc[mf][nf][rr];
                const size_t ro = (size_t)(row + rr);
                v += b0p[col];
                v += b2f(*(const unsigned short*)&hres[ro * D_ + col]);
                of32[ro * D_ + col] = v;
            }
        }
    }
    (void)obf;
}

// ---------------- sliding-window attention (unchanged, verified) ----------------
__global__ __launch_bounds__(256, 2)
void k_attn(const __hip_bfloat16* __restrict__ qkv, const float* __restrict__ mask,
            const __hip_bfloat16* __restrict__ vtg, __hip_bfloat16* __restrict__ attnb) {
    constexpr int PS = 296;
    __shared__ __hip_bfloat16 P[4][16 * PS];
    const int tid = threadIdx.x, wave = tid >> 6, lane = tid & 63;
    const int bh = blockIdx.y, b = bh >> 4, h = bh & 15;
    const int q0 = blockIdx.x * 64 + wave * 16;
    const int lo = lane & 15, hi = lane >> 4;

    short8 qf0, qf1;
    {
        const __hip_bfloat16* qb = qkv + (size_t)(b * L_ + q0 + lo) * NQKV + h * DH + hi * 8;
        qf0 = *(const short8*)qb;
        qf1 = *(const short8*)(qb + 32);
    }

    floatx4 sc[17];
    const __hip_bfloat16* kcol = qkv + (size_t)b * L_ * NQKV + D_ + h * DH + hi * 8;
#pragma unroll
    for (int t = 0; t < 17; t++) {
        int jg = q0 - 128 + t * 16 + lo;
        int jc = jg < 0 ? 0 : (jg >= L_ ? L_ - 1 : jg);
        const __hip_bfloat16* kb = kcol + (size_t)jc * NQKV;
        short8 kf0 = *(const short8*)kb;
        short8 kf1 = *(const short8*)(kb + 32);
        floatx4 a = {};
        a = __builtin_amdgcn_mfma_f32_16x16x32_bf16(qf0, kf0, a, 0, 0, 0);
        a = __builtin_amdgcn_mfma_f32_16x16x32_bf16(qf1, kf1, a, 0, 0, 0);
        float mval = mask[b * L_ + jc];
        bool jok = (jg >= 0) && (jg < L_) && (mval == 0.0f);
#pragma unroll
        for (int r = 0; r < 4; r++) {
            int qi = q0 + hi * 4 + r;
            bool ok = jok && (jg >= qi - 128) && (jg <= qi + 128);
            a[r] = ok ? a[r] * 0.125f : -1e9f;
        }
        sc[t] = a;
    }

#pragma unroll
    for (int r = 0; r < 4; r++) {
        float m = -3e38f;
#pragma unroll
        for (int t = 0; t < 17; t++) m = fmaxf(m, sc[t][r]);
        m = fmaxf(m, __shfl_xor(m, 1));
        m = fmaxf(m, __shfl_xor(m, 2));
        m = fmaxf(m, __shfl_xor(m, 4));
        m = fmaxf(m, __shfl_xor(m, 8));
        float s = 0.0f;
#pragma unroll
        for (int t = 0; t < 17; t++) { float e = __expf(sc[t][r] - m); sc[t][r] = e; s += e; }
        s += __shfl_xor(s, 1); s += __shfl_xor(s, 2);
        s += __shfl_xor(s, 4); s += __shfl_xor(s, 8);
        float inv = 1.0f / s;
#pragma unroll
        for (int t = 0; t < 17; t++) sc[t][r] *= inv;
    }

    __hip_bfloat16* Pw = &P[wave][0];
#pragma unroll
    for (int t = 0; t < 17; t++)
#pragma unroll
        for (int r = 0; r < 4; r++)
            Pw[(hi * 4 + r) * PS + t * 16 + lo] = __float2bfloat16(sc[t][r]);
    {
        int zr = lane >> 2, zc = 272 + (lane & 3) * 4;
        __hip_bfloat16 z = __float2bfloat16(0.0f);
#pragma unroll
        for (int i = 0; i < 4; i++) Pw[zr * PS + zc + i] = z;
    }

    floatx4 o[4] = {};
#pragma unroll
    for (int st = 0; st < 9; st++) {
        short8 pa = *(const short8*)(Pw + lo * PS + st * 32 + hi * 8);
        int jb = q0 - 128 + st * 32 + hi * 8;
#pragma unroll
        for (int dt = 0; dt < 4; dt++) {
            const __hip_bfloat16* vb = vtg + (long)(bh * DH + dt * 16 + lo) * L_ + jb;
            short8 vf = *(const short8*)vb;
            o[dt] = __builtin_amdgcn_mfma_f32_16x16x32_bf16(pa, vf, o[dt], 0, 0, 0);
        }
    }

#pragma unroll
    for (int dt = 0; dt < 4; dt++)
#pragma unroll
        for (int r = 0; r < 4; r++) {
            int row = q0 + hi * 4 + r;
            attnb[(size_t)(b * L_ + row) * D_ + h * DH + dt * 16 + lo] =
                __float2bfloat16(o[dt][r]);
        }
}

// ---------------- residual + LayerNorm ----------------
__global__ __launch_bounds__(256)
void k_ln(const float* __restrict__ x, const __hip_bfloat16* __restrict__ attnb,
          const float* __restrict__ g, const float* __restrict__ bt,
          __hip_bfloat16* __restrict__ hb) {
    const int row = blockIdx.x, tid = threadIdx.x;
    const int c4 = tid * 4;
    float4 xv = *(const float4*)(x + (size_t)row * D_ + c4);
    short4v av = *(const short4v*)(attnb + (size_t)row * D_ + c4);
    float h0 = xv.x + b2f((unsigned short)av[0]);
    float h1 = xv.y + b2f((unsigned short)av[1]);
    float h2 = xv.z + b2f((unsigned short)av[2]);
    float h3 = xv.w + b2f((unsigned short)av[3]);
    float s = h0 + h1 + h2 + h3;
    float q = h0 * h0 + h1 * h1 + h2 * h2 + h3 * h3;
#pragma unroll
    for (int off = 32; off > 0; off >>= 1) {
        s += __shfl_down(s, off);
        q += __shfl_down(q, off);
    }
    __shared__ float red[8];
    int wave = tid >> 6, lane = tid & 63;
    if (lane == 0) { red[wave] = s; red[4 + wave] = q; }
    __syncthreads();
    s = red[0] + red[1] + red[2] + red[3];
    q = red[4] + red[5] + red[6] + red[7];
    float mu = s * (1.0f / D_);
    float var = q * (1.0f / D_) - mu * mu;
    float inv = rsqrtf(var + 1e-5f);
    float4 gv = *(const float4*)(g + c4);
    float4 bv = *(const float4*)(bt + c4);
    alignas(8) __hip_bfloat16 ov[4];
    ov[0] = __float2bfloat16((h0 - mu) * inv * gv.x + bv.x);
    ov[1] = __float2bfloat16((h1 - mu) * inv * gv.y + bv.y);
    ov[2] = __float2bfloat16((h2 - mu) * inv * gv.z + bv.z);
    ov[3] = __float2bfloat16((h3 - mu) * inv * gv.w + bv.w);
    *(short4v*)(hb + (size_t)row * D_ + c4) = *(const short4v*)ov;
}

// ---------------- launch ----------------
extern "C" void kernel_launch(void* const* d_in, const int* in_sizes, int n_in,
                              void* d_out, int out_size, void* d_ws, size_t ws_size,
                              hipStream_t stream) {
    const float* x    = (const float*)d_in[0];
    const float* mask = (const float*)d_in[1];
    const float* Wq   = (const float*)d_in[2];
    const float* bq   = (const float*)d_in[3];
    const float* Wk   = (const float*)d_in[4];
    const float* bk   = (const float*)d_in[5];
    const float* Wv   = (const float*)d_in[6];
    const float* bv   = (const float*)d_in[7];
    const float* ln_g = (const float*)d_in[8];
    const float* ln_b = (const float*)d_in[9];
    const float* W1   = (const float*)d_in[10];
    const float* b1   = (const float*)d_in[11];
    const float* W2   = (const float*)d_in[12];
    const float* b2   = (const float*)d_in[13];
    float* out = (float*)d_out;
    char* ws = (char*)d_ws;

    __hip_bfloat16* xb   = (__hip_bfloat16*)(ws + OFF_XB);
    __hip_bfloat16* wct  = (__hip_bfloat16*)(ws + OFF_WCT);
    __hip_bfloat16* w1t  = (__hip_bfloat16*)(ws + OFF_W1T);
    __hip_bfloat16* w2t  = (__hip_bfloat16*)(ws + OFF_W2T);
    __hip_bfloat16* qkvb = (__hip_bfloat16*)(ws + OFF_QKV);
    __hip_bfloat16* vtg  = (__hip_bfloat16*)(ws + OFF_VT) + VT_GUARD;
    __hip_bfloat16* attb = (__hip_bfloat16*)(ws + OFF_ATT);
    __hip_bfloat16* hb   = (__hip_bfloat16*)(ws + OFF_HB);
    __hip_bfloat16* midb = (__hip_bfloat16*)(ws + OFF_MID);

    // input conversions
    k_cvt_x<<<(M_ * D_) / 2048, 256, 0, stream>>>(x, xb);
    k_tcvt<<<dim3(D_ / 64, D_ / 64), 256, 0, stream>>>(Wq, wct,                   D_, D_);
    k_tcvt<<<dim3(D_ / 64, D_ / 64), 256, 0, stream>>>(Wk, wct + 1024 * 1024,     D_, D_);
    k_tcvt<<<dim3(D_ / 64, D_ / 64), 256, 0, stream>>>(Wv, wct + 2 * 1024 * 1024, D_, D_);
    k_tcvt<<<dim3(F_ / 64, D_ / 64), 256, 0, stream>>>(W1, w1t, D_, F_);
    k_tcvt<<<dim3(D_ / 64, F_ / 64), 256, 0, stream>>>(W2, w2t, F_, D_);

    // fused QKV projection: BM=128, BN=256 -> grid 64*12 = 768
    k_w8<8, 0, 12><<<768, 256, 0, stream>>>(xb, wct, bq, bk, bv, qkvb, nullptr);

    // V transpose, attention
    k_vtrans<<<dim3(L_ / 64, B_ * H_), 256, 0, stream>>>(qkvb, vtg);
    k_attn<<<dim3(L_ / 64, B_ * H_), 256, 0, stream>>>(qkvb, mask, vtg, attb);

    // residual + LN
    k_ln<<<M_, 256, 0, stream>>>(x, attb, ln_g, ln_b, hb);

    // FFN1: BM=128, BN=256 -> grid 64*16 = 1024
    k_w8<8, 1, 16><<<1024, 256, 0, stream>>>(hb, w1t, b1, nullptr, nullptr, midb, nullptr);
    // FFN2 (control, R8 config): BM=128, BN=128, NT=256 -> grid 64*8 = 512
    k_p3<256, 2, 2, 2, F_, 8, 3><<<512, 256, 0, stream>>>(
        midb, w2t, b2, nullptr, out, hb);
}